// Round 1
// baseline (863.047 us; speedup 1.0000x reference)
//
#include <hip/hip_runtime.h>
#include <hip/hip_bf16.h>
#include <math.h>

// ---------------------------------------------------------------------------
// NodeMLPModel: edge MLP (GEMM+BN+SELU+GEMM) -> scatter-mean -> node MLP.
// bf16 MFMA (16x16x32) with f32 accum; weights pre-packed in fragment order.
// Fragment layout (m89/m91-verified):
//   A: lane holds A[lane&15][8*(lane>>4)+j], j=0..7
//   B: lane holds B[8*(lane>>4)+j][lane&15]
//   D: lane holds D[4*(lane>>4)+r][lane&15], r=0..3
// ---------------------------------------------------------------------------

typedef __attribute__((ext_vector_type(8))) short bfrag;
typedef __attribute__((ext_vector_type(4))) float f32x4;

#define N_EDGES 800000
#define N_NODES 100000

static __device__ __forceinline__ short f2bf(float f) {
    union { float f; unsigned u; } v; v.f = f;
    unsigned r = (v.u + 0x7FFFu + ((v.u >> 16) & 1u)) >> 16;  // RNE
    return (short)r;
}
static __device__ __forceinline__ float bf2f(short h) {
    union { unsigned u; float f; } v;
    v.u = ((unsigned)(unsigned short)h) << 16;
    return v.f;
}

static __device__ __forceinline__ bfrag load8f_bf(const float* __restrict__ p, float s) {
    float4 a = *(const float4*)p;
    float4 b = *(const float4*)(p + 4);
    bfrag r;
    r[0] = f2bf(a.x * s); r[1] = f2bf(a.y * s); r[2] = f2bf(a.z * s); r[3] = f2bf(a.w * s);
    r[4] = f2bf(b.x * s); r[5] = f2bf(b.y * s); r[6] = f2bf(b.z * s); r[7] = f2bf(b.w * s);
    return r;
}

// Pack W[K][128] f32 row-major -> bf16 fragment order:
// Wp[(((kb*128 + n)*4 + g)*8 + j)] = W[kb*32 + g*8 + j][n]
__global__ void pack_w(const float* __restrict__ W, short* __restrict__ Wp, int K) {
    int idx = blockIdx.x * 256 + threadIdx.x;
    if (idx >= K * 128) return;
    int k = idx >> 7, n = idx & 127;
    int kb = k >> 5, g = (k >> 3) & 3, j = k & 7;
    Wp[(((size_t)kb * 128 + n) * 4 + g) * 8 + j] = f2bf(W[idx]);
}

__global__ void cnt_k(const int* __restrict__ colIdx, float* __restrict__ CNT, int E) {
    int i = blockIdx.x * 256 + threadIdx.x;
    if (i < E) atomicAdd(&CNT[colIdx[i]], 1.0f);
}

// Edge GEMM1: T1[e][:] = concat(x[row[e]], edge_attr[e]) @ W1a   (bias skipped: cancels in BN)
__global__ __launch_bounds__(256) void gemm1_edge(
    const float* __restrict__ x, const float* __restrict__ ea,
    const int* __restrict__ rowIdx, const short* __restrict__ Wp,
    short* __restrict__ T1, int E)
{
    const int lane = threadIdx.x & 63, wave = threadIdx.x >> 6;
    const int m0 = blockIdx.x * 128 + wave * 32;
    if (m0 >= E) return;
    const int lr = lane & 15, lg = lane >> 4;
    const int e0 = m0 + lr, e1 = m0 + 16 + lr;
    const float* xr0 = x + (size_t)rowIdx[e0] * 128;
    const float* xr1 = x + (size_t)rowIdx[e1] * 128;
    const float* er0 = ea + (size_t)e0 * 64;
    const float* er1 = ea + (size_t)e1 * 64;

    f32x4 acc[2][8];
#pragma unroll
    for (int t = 0; t < 2; ++t)
#pragma unroll
        for (int n = 0; n < 8; ++n) acc[t][n] = (f32x4){0.f, 0.f, 0.f, 0.f};

#pragma unroll
    for (int kb = 0; kb < 6; ++kb) {
        const float *p0, *p1;
        if (kb < 4) { p0 = xr0 + kb * 32 + lg * 8; p1 = xr1 + kb * 32 + lg * 8; }
        else        { p0 = er0 + (kb - 4) * 32 + lg * 8; p1 = er1 + (kb - 4) * 32 + lg * 8; }
        bfrag a0 = load8f_bf(p0, 1.0f);
        bfrag a1 = load8f_bf(p1, 1.0f);
        const short* wb = Wp + (size_t)kb * 4096;
#pragma unroll
        for (int n0 = 0; n0 < 8; ++n0) {
            bfrag b = *(const bfrag*)(wb + ((n0 * 16 + lr) * 4 + lg) * 8);
            acc[0][n0] = __builtin_amdgcn_mfma_f32_16x16x32_bf16(a0, b, acc[0][n0], 0, 0, 0);
            acc[1][n0] = __builtin_amdgcn_mfma_f32_16x16x32_bf16(a1, b, acc[1][n0], 0, 0, 0);
        }
    }
#pragma unroll
    for (int t = 0; t < 2; ++t) {
        const int rbase = m0 + t * 16 + lg * 4;
#pragma unroll
        for (int n0 = 0; n0 < 8; ++n0) {
            const int c = n0 * 16 + lr;
#pragma unroll
            for (int r = 0; r < 4; ++r)
                T1[(size_t)(rbase + r) * 128 + c] = f2bf(acc[t][n0][r]);
        }
    }
}

// Column sums + sumsq of bf16 matrix T[R][128] -> stats[0:128]=sum, stats[128:256]=sumsq
__global__ __launch_bounds__(256) void col_stats(const short* __restrict__ T, int R,
                                                 float* __restrict__ stats)
{
    const int cb = threadIdx.x & 15, rl = threadIdx.x >> 4;
    float s[8], ss[8];
#pragma unroll
    for (int j = 0; j < 8; ++j) { s[j] = 0.f; ss[j] = 0.f; }
    for (int r = blockIdx.x * 16 + rl; r < R; r += gridDim.x * 16) {
        bfrag v = *(const bfrag*)(T + (size_t)r * 128 + cb * 8);
#pragma unroll
        for (int j = 0; j < 8; ++j) { float f = bf2f(v[j]); s[j] += f; ss[j] += f * f; }
    }
    __shared__ float ls[256];
    ls[threadIdx.x] = 0.f;
    __syncthreads();
#pragma unroll
    for (int j = 0; j < 8; ++j) {
        atomicAdd(&ls[cb * 8 + j], s[j]);
        atomicAdd(&ls[128 + cb * 8 + j], ss[j]);
    }
    __syncthreads();
    atomicAdd(&stats[threadIdx.x], ls[threadIdx.x]);
}

// scale/shift from stats: bnp[0:128]=scale, bnp[128:256]=shift
__global__ void bn_final(const float* __restrict__ stats, const float* __restrict__ g,
                         const float* __restrict__ be, float* __restrict__ bnp, float invR)
{
    int j = threadIdx.x;
    float mean = stats[j] * invR;
    float var = stats[128 + j] * invR - mean * mean;
    float sc = g[j] * rsqrtf(var + 1e-5f);
    bnp[j] = sc;
    bnp[128 + j] = be[j] - mean * sc;
}

static __device__ __forceinline__ float selu_f(float v) {
    return v > 0.f ? 1.0507009873554805f * v : 1.7580993408473766f * expm1f(v);
}

// Edge GEMM2: selu(BN(T1)) @ W1b + b1b, scatter-add into S by colIdx
__global__ __launch_bounds__(256) void gemm2_edge(
    const short* __restrict__ T1, const float* __restrict__ bnp,
    const short* __restrict__ Wp, const float* __restrict__ b1b,
    const int* __restrict__ colIdx, float* __restrict__ S, int E)
{
    const int lane = threadIdx.x & 63, wave = threadIdx.x >> 6;
    const int m0 = blockIdx.x * 128 + wave * 32;
    if (m0 >= E) return;
    const int lr = lane & 15, lg = lane >> 4;
    const int e0 = m0 + lr, e1 = m0 + 16 + lr;

    f32x4 acc[2][8];
#pragma unroll
    for (int n0 = 0; n0 < 8; ++n0) {
        float bias = b1b[n0 * 16 + lr];
        acc[0][n0] = (f32x4){bias, bias, bias, bias};
        acc[1][n0] = (f32x4){bias, bias, bias, bias};
    }
#pragma unroll
    for (int kb = 0; kb < 4; ++kb) {
        const int koff = kb * 32 + lg * 8;
        float4 sc0 = *(const float4*)(bnp + koff);
        float4 sc1 = *(const float4*)(bnp + koff + 4);
        float4 sh0 = *(const float4*)(bnp + 128 + koff);
        float4 sh1 = *(const float4*)(bnp + 128 + koff + 4);
        float scl[8] = {sc0.x, sc0.y, sc0.z, sc0.w, sc1.x, sc1.y, sc1.z, sc1.w};
        float shf[8] = {sh0.x, sh0.y, sh0.z, sh0.w, sh1.x, sh1.y, sh1.z, sh1.w};
        bfrag r0 = *(const bfrag*)(T1 + (size_t)e0 * 128 + koff);
        bfrag r1 = *(const bfrag*)(T1 + (size_t)e1 * 128 + koff);
        bfrag a0, a1;
#pragma unroll
        for (int j = 0; j < 8; ++j) {
            a0[j] = f2bf(selu_f(bf2f(r0[j]) * scl[j] + shf[j]));
            a1[j] = f2bf(selu_f(bf2f(r1[j]) * scl[j] + shf[j]));
        }
        const short* wb = Wp + (size_t)kb * 4096;
#pragma unroll
        for (int n0 = 0; n0 < 8; ++n0) {
            bfrag b = *(const bfrag*)(wb + ((n0 * 16 + lr) * 4 + lg) * 8);
            acc[0][n0] = __builtin_amdgcn_mfma_f32_16x16x32_bf16(a0, b, acc[0][n0], 0, 0, 0);
            acc[1][n0] = __builtin_amdgcn_mfma_f32_16x16x32_bf16(a1, b, acc[1][n0], 0, 0, 0);
        }
    }
#pragma unroll
    for (int t = 0; t < 2; ++t) {
        int cr[4];
#pragma unroll
        for (int r = 0; r < 4; ++r) cr[r] = colIdx[m0 + t * 16 + lg * 4 + r];
#pragma unroll
        for (int n0 = 0; n0 < 8; ++n0) {
            const int c = n0 * 16 + lr;
#pragma unroll
            for (int r = 0; r < 4; ++r)
                atomicAdd(&S[(size_t)cr[r] * 128 + c], acc[t][n0][r]);
        }
    }
}

// Node GEMM1: T2 = concat(x, S/max(cnt,1), u[batch]) @ W2a  (bias skipped: cancels in BN)
__global__ __launch_bounds__(256) void gemm3_node(
    const float* __restrict__ x, const float* __restrict__ S, const float* __restrict__ CNT,
    const float* __restrict__ u, const int* __restrict__ batch,
    const short* __restrict__ Wp, short* __restrict__ T2, int N)
{
    const int lane = threadIdx.x & 63, wave = threadIdx.x >> 6;
    const int m0 = blockIdx.x * 128 + wave * 32;
    if (m0 >= N) return;
    const int lr = lane & 15, lg = lane >> 4;
    const int v0 = m0 + lr, v1 = m0 + 16 + lr;
    const float inv0 = 1.0f / fmaxf(CNT[v0], 1.0f);
    const float inv1 = 1.0f / fmaxf(CNT[v1], 1.0f);
    const float* u0 = u + (size_t)batch[v0] * 128;
    const float* u1 = u + (size_t)batch[v1] * 128;

    f32x4 acc[2][8];
#pragma unroll
    for (int t = 0; t < 2; ++t)
#pragma unroll
        for (int n = 0; n < 8; ++n) acc[t][n] = (f32x4){0.f, 0.f, 0.f, 0.f};

#pragma unroll
    for (int kb = 0; kb < 12; ++kb) {
        const float *p0, *p1;
        float s0 = 1.0f, s1 = 1.0f;
        if (kb < 4) {
            p0 = x + (size_t)v0 * 128 + kb * 32 + lg * 8;
            p1 = x + (size_t)v1 * 128 + kb * 32 + lg * 8;
        } else if (kb < 8) {
            p0 = S + (size_t)v0 * 128 + (kb - 4) * 32 + lg * 8; s0 = inv0;
            p1 = S + (size_t)v1 * 128 + (kb - 4) * 32 + lg * 8; s1 = inv1;
        } else {
            p0 = u0 + (kb - 8) * 32 + lg * 8;
            p1 = u1 + (kb - 8) * 32 + lg * 8;
        }
        bfrag a0 = load8f_bf(p0, s0);
        bfrag a1 = load8f_bf(p1, s1);
        const short* wb = Wp + (size_t)kb * 4096;
#pragma unroll
        for (int n0 = 0; n0 < 8; ++n0) {
            bfrag b = *(const bfrag*)(wb + ((n0 * 16 + lr) * 4 + lg) * 8);
            acc[0][n0] = __builtin_amdgcn_mfma_f32_16x16x32_bf16(a0, b, acc[0][n0], 0, 0, 0);
            acc[1][n0] = __builtin_amdgcn_mfma_f32_16x16x32_bf16(a1, b, acc[1][n0], 0, 0, 0);
        }
    }
#pragma unroll
    for (int t = 0; t < 2; ++t) {
        const int rbase = m0 + t * 16 + lg * 4;
#pragma unroll
        for (int n0 = 0; n0 < 8; ++n0) {
            const int c = n0 * 16 + lr;
#pragma unroll
            for (int r = 0; r < 4; ++r)
                T2[(size_t)(rbase + r) * 128 + c] = f2bf(acc[t][n0][r]);
        }
    }
}

// Node GEMM2: out = selu(BN(T2)) @ W2b + b2b   (f32 output)
__global__ __launch_bounds__(256) void gemm4_node(
    const short* __restrict__ T2, const float* __restrict__ bnp,
    const short* __restrict__ Wp, const float* __restrict__ b2b,
    float* __restrict__ out, int N)
{
    const int lane = threadIdx.x & 63, wave = threadIdx.x >> 6;
    const int m0 = blockIdx.x * 128 + wave * 32;
    if (m0 >= N) return;
    const int lr = lane & 15, lg = lane >> 4;
    const int e0 = m0 + lr, e1 = m0 + 16 + lr;

    f32x4 acc[2][8];
#pragma unroll
    for (int n0 = 0; n0 < 8; ++n0) {
        float bias = b2b[n0 * 16 + lr];
        acc[0][n0] = (f32x4){bias, bias, bias, bias};
        acc[1][n0] = (f32x4){bias, bias, bias, bias};
    }
#pragma unroll
    for (int kb = 0; kb < 4; ++kb) {
        const int koff = kb * 32 + lg * 8;
        float4 sc0 = *(const float4*)(bnp + koff);
        float4 sc1 = *(const float4*)(bnp + koff + 4);
        float4 sh0 = *(const float4*)(bnp + 128 + koff);
        float4 sh1 = *(const float4*)(bnp + 128 + koff + 4);
        float scl[8] = {sc0.x, sc0.y, sc0.z, sc0.w, sc1.x, sc1.y, sc1.z, sc1.w};
        float shf[8] = {sh0.x, sh0.y, sh0.z, sh0.w, sh1.x, sh1.y, sh1.z, sh1.w};
        bfrag r0 = *(const bfrag*)(T2 + (size_t)e0 * 128 + koff);
        bfrag r1 = *(const bfrag*)(T2 + (size_t)e1 * 128 + koff);
        bfrag a0, a1;
#pragma unroll
        for (int j = 0; j < 8; ++j) {
            a0[j] = f2bf(selu_f(bf2f(r0[j]) * scl[j] + shf[j]));
            a1[j] = f2bf(selu_f(bf2f(r1[j]) * scl[j] + shf[j]));
        }
        const short* wb = Wp + (size_t)kb * 4096;
#pragma unroll
        for (int n0 = 0; n0 < 8; ++n0) {
            bfrag b = *(const bfrag*)(wb + ((n0 * 16 + lr) * 4 + lg) * 8);
            acc[0][n0] = __builtin_amdgcn_mfma_f32_16x16x32_bf16(a0, b, acc[0][n0], 0, 0, 0);
            acc[1][n0] = __builtin_amdgcn_mfma_f32_16x16x32_bf16(a1, b, acc[1][n0], 0, 0, 0);
        }
    }
#pragma unroll
    for (int t = 0; t < 2; ++t) {
        const int rbase = m0 + t * 16 + lg * 4;
#pragma unroll
        for (int n0 = 0; n0 < 8; ++n0) {
            const int c = n0 * 16 + lr;
#pragma unroll
            for (int r = 0; r < 4; ++r)
                out[(size_t)(rbase + r) * 128 + c] = acc[t][n0][r];
        }
    }
}

// ---------------------------------------------------------------------------
// Workspace layout (bytes):
//   0        Wp1a (49152)      | 49152   Wp1b (32768) | 81920  Wp2a (98304)
//   180224   Wp2b (32768)      | 212992  stats1(1024) | 214016 bnp1 (1024)
//   215040   stats2 (1024)     | 216064  bnp2  (1024)
//   217088   T1  bf16 800000x128 (204800000)
//   205017088 S   f32 100000x128 (51200000)
//   256217088 CNT f32 100000    (400000)
//   256617088 T2  bf16 100000x128 (25600000)
//   total: 282217088
// ---------------------------------------------------------------------------
extern "C" void kernel_launch(void* const* d_in, const int* in_sizes, int n_in,
                              void* d_out, int out_size, void* d_ws, size_t ws_size,
                              hipStream_t stream)
{
    const float* x   = (const float*)d_in[0];
    const float* ea  = (const float*)d_in[1];
    const float* u   = (const float*)d_in[2];
    const float* W1a = (const float*)d_in[3];
    // d_in[4] = b1a: unused (bias before BN cancels exactly)
    const float* g1  = (const float*)d_in[5];
    const float* be1 = (const float*)d_in[6];
    const float* W1b = (const float*)d_in[7];
    const float* b1b = (const float*)d_in[8];
    const float* W2a = (const float*)d_in[9];
    // d_in[10] = b2a: unused
    const float* g2  = (const float*)d_in[11];
    const float* be2 = (const float*)d_in[12];
    const float* W2b = (const float*)d_in[13];
    const float* b2b = (const float*)d_in[14];
    const int* ei    = (const int*)d_in[15];
    const int* rowI  = ei;
    const int* colI  = ei + N_EDGES;
    const int* batch = (const int*)d_in[16];
    float* out = (float*)d_out;

    if (ws_size < 282217088ull) return;  // would corrupt memory; fail visibly (absmax=ref max)

    char* ws = (char*)d_ws;
    short* Wp1a   = (short*)(ws + 0);
    short* Wp1b   = (short*)(ws + 49152);
    short* Wp2a   = (short*)(ws + 81920);
    short* Wp2b   = (short*)(ws + 180224);
    float* stats1 = (float*)(ws + 212992);
    float* bnp1   = (float*)(ws + 214016);
    float* stats2 = (float*)(ws + 215040);
    float* bnp2   = (float*)(ws + 216064);
    short* T1     = (short*)(ws + 217088);
    float* S      = (float*)(ws + 205017088ull);
    float* CNT    = (float*)(ws + 256217088ull);
    short* T2     = (short*)(ws + 256617088ull);

    hipMemsetAsync(stats1, 0, 4096, stream);               // stats1,bnp1,stats2,bnp2
    hipMemsetAsync(S, 0, (size_t)N_NODES * 128 * 4, stream);
    hipMemsetAsync(CNT, 0, (size_t)N_NODES * 4, stream);

    pack_w<<<96, 256, 0, stream>>>(W1a, Wp1a, 192);
    pack_w<<<64, 256, 0, stream>>>(W1b, Wp1b, 128);
    pack_w<<<192, 256, 0, stream>>>(W2a, Wp2a, 384);
    pack_w<<<64, 256, 0, stream>>>(W2b, Wp2b, 128);
    cnt_k<<<(N_EDGES + 255) / 256, 256, 0, stream>>>(colI, CNT, N_EDGES);

    gemm1_edge<<<N_EDGES / 128, 256, 0, stream>>>(x, ea, rowI, Wp1a, T1, N_EDGES);
    col_stats<<<1024, 256, 0, stream>>>(T1, N_EDGES, stats1);
    bn_final<<<1, 128, 0, stream>>>(stats1, g1, be1, bnp1, 1.0f / (float)N_EDGES);
    gemm2_edge<<<N_EDGES / 128, 256, 0, stream>>>(T1, bnp1, Wp1b, b1b, colI, S, N_EDGES);

    gemm3_node<<<(N_NODES + 127) / 128, 256, 0, stream>>>(x, S, CNT, u, batch, Wp2a, T2, N_NODES);
    col_stats<<<256, 256, 0, stream>>>(T2, N_NODES, stats2);
    bn_final<<<1, 128, 0, stream>>>(stats2, g2, be2, bnp2, 1.0f / (float)N_NODES);
    gemm4_node<<<(N_NODES + 127) / 128, 256, 0, stream>>>(T2, bnp2, Wp2b, b2b, out, N_NODES);
}

// Round 2
// 725.340 us; speedup vs baseline: 1.1899x; 1.1899x over previous
//
#include <hip/hip_runtime.h>
#include <hip/hip_bf16.h>
#include <math.h>

// ---------------------------------------------------------------------------
// NodeMLPModel: edge MLP (GEMM+BN+SELU+GEMM) -> scatter-mean -> node MLP.
// bf16 MFMA 16x16x32, f32 accum. CSR bucketing + segmented sum (no f32 atomic
// scatter). Column stats fused into GEMM epilogues. gemm2 writes in-place
// over T1.
// Fragment layout (m89/m91-verified):
//   A: lane holds A[lane&15][8*(lane>>4)+j]
//   B: lane holds B[8*(lane>>4)+j][lane&15]
//   D: lane holds D[4*(lane>>4)+r][lane&15]
// ---------------------------------------------------------------------------

typedef __attribute__((ext_vector_type(8))) short bfrag;
typedef __attribute__((ext_vector_type(4))) float f32x4;

#define N_EDGES 800000
#define N_NODES 100000

static __device__ __forceinline__ short f2bf(float f) {
    union { float f; unsigned u; } v; v.f = f;
    unsigned r = (v.u + 0x7FFFu + ((v.u >> 16) & 1u)) >> 16;  // RNE
    return (short)r;
}
static __device__ __forceinline__ float bf2f(short h) {
    union { unsigned u; float f; } v;
    v.u = ((unsigned)(unsigned short)h) << 16;
    return v.f;
}
static __device__ __forceinline__ unsigned pack2(float lo, float hi) {
    return ((unsigned)(unsigned short)f2bf(lo)) | (((unsigned)(unsigned short)f2bf(hi)) << 16);
}

static __device__ __forceinline__ bfrag load8f_bf(const float* __restrict__ p) {
    float4 a = *(const float4*)p;
    float4 b = *(const float4*)(p + 4);
    bfrag r;
    r[0] = f2bf(a.x); r[1] = f2bf(a.y); r[2] = f2bf(a.z); r[3] = f2bf(a.w);
    r[4] = f2bf(b.x); r[5] = f2bf(b.y); r[6] = f2bf(b.z); r[7] = f2bf(b.w);
    return r;
}

// Pack W[K][128] f32 row-major -> bf16 fragment order:
// Wp[(((kb*128 + n)*4 + g)*8 + j)] = W[kb*32 + g*8 + j][n]
__global__ void pack_w(const float* __restrict__ W, short* __restrict__ Wp, int K) {
    int idx = blockIdx.x * 256 + threadIdx.x;
    if (idx >= K * 128) return;
    int k = idx >> 7, n = idx & 127;
    int kb = k >> 5, g = (k >> 3) & 3, j = k & 7;
    Wp[(((size_t)kb * 128 + n) * 4 + g) * 8 + j] = f2bf(W[idx]);
}

// ----------------------------- CSR build -----------------------------------
__global__ void hist_k(const int* __restrict__ col, int* __restrict__ cnt, int E) {
    int i = blockIdx.x * 256 + threadIdx.x;
    if (i < E) atomicAdd(&cnt[col[i]], 1);
}

__global__ void scan1(const int* __restrict__ cnt, int* __restrict__ off,
                      int* __restrict__ bsum, int N) {
    __shared__ int ls[1024];
    int i = blockIdx.x * 1024 + threadIdx.x;
    int v = (i < N) ? cnt[i] : 0;
    ls[threadIdx.x] = v;
    __syncthreads();
    for (int d = 1; d < 1024; d <<= 1) {
        int t = (threadIdx.x >= d) ? ls[threadIdx.x - d] : 0;
        __syncthreads();
        ls[threadIdx.x] += t;
        __syncthreads();
    }
    if (i < N) off[i] = ls[threadIdx.x] - v;  // block-local exclusive
    if (threadIdx.x == 1023) bsum[blockIdx.x] = ls[1023];
}

__global__ void scan2(const int* __restrict__ bsum, int* __restrict__ boff, int NB) {
    __shared__ int ls[128];
    int v = (threadIdx.x < NB) ? bsum[threadIdx.x] : 0;
    ls[threadIdx.x] = v;
    __syncthreads();
    for (int d = 1; d < 128; d <<= 1) {
        int t = (threadIdx.x >= d) ? ls[threadIdx.x - d] : 0;
        __syncthreads();
        ls[threadIdx.x] += t;
        __syncthreads();
    }
    if (threadIdx.x < NB) boff[threadIdx.x] = ls[threadIdx.x] - v;  // exclusive
}

__global__ void scan3(int* __restrict__ off, const int* __restrict__ boff, int N) {
    int i = blockIdx.x * 1024 + threadIdx.x;
    if (i < N) off[i] += boff[blockIdx.x];
}

__global__ void fill_k(const int* __restrict__ col, const int* __restrict__ off,
                       int* __restrict__ cur, int* __restrict__ perm, int E) {
    int e = blockIdx.x * 256 + threadIdx.x;
    if (e < E) {
        int c = col[e];
        int p = atomicAdd(&cur[c], 1);
        perm[off[c] + p] = e;
    }
}

// ---------------------------------------------------------------------------
// Edge GEMM1: T1 = concat(x[row], ea) @ W1a ; fused column sum/sumsq -> stats
__global__ __launch_bounds__(256) void gemm1_edge(
    const float* __restrict__ x, const float* __restrict__ ea,
    const int* __restrict__ rowIdx, const short* __restrict__ Wp,
    short* __restrict__ T1, float* __restrict__ stats, int E)
{
    const int lane = threadIdx.x & 63, wave = threadIdx.x >> 6;
    const int m0 = blockIdx.x * 128 + wave * 32;   // E % 128 == 0: always active
    const int lr = lane & 15, lg = lane >> 4;
    __shared__ float ls[256];
    ls[threadIdx.x] = 0.f;
    __syncthreads();

    const int e0 = m0 + lr, e1 = m0 + 16 + lr;
    const float* xr0 = x + (size_t)rowIdx[e0] * 128;
    const float* xr1 = x + (size_t)rowIdx[e1] * 128;
    const float* er0 = ea + (size_t)e0 * 64;
    const float* er1 = ea + (size_t)e1 * 64;

    f32x4 acc[2][8];
#pragma unroll
    for (int t = 0; t < 2; ++t)
#pragma unroll
        for (int n = 0; n < 8; ++n) acc[t][n] = (f32x4){0.f, 0.f, 0.f, 0.f};

#pragma unroll
    for (int kb = 0; kb < 6; ++kb) {
        const float *p0, *p1;
        if (kb < 4) { p0 = xr0 + kb * 32 + lg * 8; p1 = xr1 + kb * 32 + lg * 8; }
        else        { p0 = er0 + (kb - 4) * 32 + lg * 8; p1 = er1 + (kb - 4) * 32 + lg * 8; }
        bfrag a0 = load8f_bf(p0);
        bfrag a1 = load8f_bf(p1);
        const short* wb = Wp + (size_t)kb * 4096;
#pragma unroll
        for (int n0 = 0; n0 < 8; ++n0) {
            bfrag b = *(const bfrag*)(wb + ((n0 * 16 + lr) * 4 + lg) * 8);
            acc[0][n0] = __builtin_amdgcn_mfma_f32_16x16x32_bf16(a0, b, acc[0][n0], 0, 0, 0);
            acc[1][n0] = __builtin_amdgcn_mfma_f32_16x16x32_bf16(a1, b, acc[1][n0], 0, 0, 0);
        }
    }
    // store + fused stats
#pragma unroll
    for (int n0 = 0; n0 < 8; ++n0) {
        const int c = n0 * 16 + lr;
        float p = 0.f, q = 0.f;
#pragma unroll
        for (int t = 0; t < 2; ++t) {
            const int rbase = m0 + t * 16 + lg * 4;
#pragma unroll
            for (int r = 0; r < 4; ++r) {
                float v = acc[t][n0][r];
                p += v; q += v * v;
                T1[(size_t)(rbase + r) * 128 + c] = f2bf(v);
            }
        }
        p += __shfl_xor(p, 16); p += __shfl_xor(p, 32);
        q += __shfl_xor(q, 16); q += __shfl_xor(q, 32);
        if (lg == 0) { atomicAdd(&ls[c], p); atomicAdd(&ls[128 + c], q); }
    }
    __syncthreads();
    atomicAdd(&stats[threadIdx.x], ls[threadIdx.x]);
}

// scale/shift from stats: bnp[0:128]=scale, bnp[128:256]=shift
__global__ void bn_final(const float* __restrict__ stats, const float* __restrict__ g,
                         const float* __restrict__ be, float* __restrict__ bnp, float invR)
{
    int j = threadIdx.x;
    float mean = stats[j] * invR;
    float var = stats[128 + j] * invR - mean * mean;
    float sc = g[j] * rsqrtf(var + 1e-5f);
    bnp[j] = sc;
    bnp[128 + j] = be[j] - mean * sc;
}

static __device__ __forceinline__ float selu_f(float v) {
    return v > 0.f ? 1.0507009873554805f * v : 1.7580993408473766f * expm1f(v);
}

// Edge GEMM2: selu(BN(T1)) @ W1b + b1b, written IN-PLACE over T1 (bf16)
__global__ __launch_bounds__(256) void gemm2_edge(
    short* __restrict__ T1, const float* __restrict__ bnp,
    const short* __restrict__ Wp, const float* __restrict__ b1b, int E)
{
    const int lane = threadIdx.x & 63, wave = threadIdx.x >> 6;
    const int m0 = blockIdx.x * 128 + wave * 32;
    const int lr = lane & 15, lg = lane >> 4;
    const int e0 = m0 + lr, e1 = m0 + 16 + lr;

    f32x4 acc[2][8];
#pragma unroll
    for (int n0 = 0; n0 < 8; ++n0) {
        float bias = b1b[n0 * 16 + lr];
        acc[0][n0] = (f32x4){bias, bias, bias, bias};
        acc[1][n0] = (f32x4){bias, bias, bias, bias};
    }
#pragma unroll
    for (int kb = 0; kb < 4; ++kb) {
        const int koff = kb * 32 + lg * 8;
        float4 sc0 = *(const float4*)(bnp + koff);
        float4 sc1 = *(const float4*)(bnp + koff + 4);
        float4 sh0 = *(const float4*)(bnp + 128 + koff);
        float4 sh1 = *(const float4*)(bnp + 128 + koff + 4);
        float scl[8] = {sc0.x, sc0.y, sc0.z, sc0.w, sc1.x, sc1.y, sc1.z, sc1.w};
        float shf[8] = {sh0.x, sh0.y, sh0.z, sh0.w, sh1.x, sh1.y, sh1.z, sh1.w};
        bfrag r0 = *(const bfrag*)(T1 + (size_t)e0 * 128 + koff);
        bfrag r1 = *(const bfrag*)(T1 + (size_t)e1 * 128 + koff);
        bfrag a0, a1;
#pragma unroll
        for (int j = 0; j < 8; ++j) {
            a0[j] = f2bf(selu_f(bf2f(r0[j]) * scl[j] + shf[j]));
            a1[j] = f2bf(selu_f(bf2f(r1[j]) * scl[j] + shf[j]));
        }
        const short* wb = Wp + (size_t)kb * 4096;
#pragma unroll
        for (int n0 = 0; n0 < 8; ++n0) {
            bfrag b = *(const bfrag*)(wb + ((n0 * 16 + lr) * 4 + lg) * 8);
            acc[0][n0] = __builtin_amdgcn_mfma_f32_16x16x32_bf16(a0, b, acc[0][n0], 0, 0, 0);
            acc[1][n0] = __builtin_amdgcn_mfma_f32_16x16x32_bf16(a1, b, acc[1][n0], 0, 0, 0);
        }
    }
    // in-place store (this wave read all of rows m0..m0+31 above)
#pragma unroll
    for (int t = 0; t < 2; ++t) {
        const int rbase = m0 + t * 16 + lg * 4;
#pragma unroll
        for (int n0 = 0; n0 < 8; ++n0) {
            const int c = n0 * 16 + lr;
#pragma unroll
            for (int r = 0; r < 4; ++r)
                T1[(size_t)(rbase + r) * 128 + c] = f2bf(acc[t][n0][r]);
        }
    }
}

// Segmented mean: Agg[v] = sum_{e in bucket(v)} T3[perm[e]] / max(cnt,1)  (bf16)
__global__ __launch_bounds__(256) void segsum(
    const short* __restrict__ T3, const int* __restrict__ off,
    const int* __restrict__ cnti, const int* __restrict__ perm,
    short* __restrict__ Agg, int N)
{
    const int lane = threadIdx.x & 63;
    const int wid = blockIdx.x * 4 + (threadIdx.x >> 6);
    const int nw = gridDim.x * 4;
    const int h = lane >> 5, t = lane & 31;   // half-wave h handles edge j+h; lane covers cols t*4..t*4+3
    for (int v = wid; v < N; v += nw) {
        const int beg = off[v], cnt = cnti[v];
        float a0 = 0.f, a1 = 0.f, a2 = 0.f, a3 = 0.f;
        for (int j = 0; j < cnt; j += 2) {
            const int jj = j + h;
            if (jj < cnt) {
                const int e = perm[beg + jj];
                uint2 w = *(const uint2*)(T3 + (size_t)e * 128 + t * 4);
                a0 += bf2f((short)(w.x & 0xffff)); a1 += bf2f((short)(w.x >> 16));
                a2 += bf2f((short)(w.y & 0xffff)); a3 += bf2f((short)(w.y >> 16));
            }
        }
        a0 += __shfl_xor(a0, 32); a1 += __shfl_xor(a1, 32);
        a2 += __shfl_xor(a2, 32); a3 += __shfl_xor(a3, 32);
        if (h == 0) {
            const float inv = 1.0f / fmaxf((float)cnt, 1.0f);
            uint2 o;
            o.x = pack2(a0 * inv, a1 * inv);
            o.y = pack2(a2 * inv, a3 * inv);
            *(uint2*)(Agg + (size_t)v * 128 + t * 4) = o;
        }
    }
}

// Node GEMM1: T2 = concat(x, Agg, u[batch]) @ W2a ; fused stats
__global__ __launch_bounds__(256) void gemm3_node(
    const float* __restrict__ x, const short* __restrict__ Agg,
    const float* __restrict__ u, const int* __restrict__ batch,
    const short* __restrict__ Wp, short* __restrict__ T2,
    float* __restrict__ stats, int N)
{
    const int lane = threadIdx.x & 63, wave = threadIdx.x >> 6;
    const int m0 = blockIdx.x * 128 + wave * 32;
    const bool active = (m0 < N);   // N % 32 == 0: wave fully valid or fully idle
    const int lr = lane & 15, lg = lane >> 4;
    __shared__ float ls[256];
    ls[threadIdx.x] = 0.f;
    __syncthreads();

    const int v0 = active ? m0 + lr : 0, v1 = active ? m0 + 16 + lr : 0;
    const float* u0 = u + (size_t)batch[v0] * 128;
    const float* u1 = u + (size_t)batch[v1] * 128;

    f32x4 acc[2][8];
#pragma unroll
    for (int t = 0; t < 2; ++t)
#pragma unroll
        for (int n = 0; n < 8; ++n) acc[t][n] = (f32x4){0.f, 0.f, 0.f, 0.f};

    if (active) {
#pragma unroll
        for (int kb = 0; kb < 12; ++kb) {
            bfrag a0, a1;
            if (kb >= 4 && kb < 8) {
                a0 = *(const bfrag*)(Agg + (size_t)v0 * 128 + (kb - 4) * 32 + lg * 8);
                a1 = *(const bfrag*)(Agg + (size_t)v1 * 128 + (kb - 4) * 32 + lg * 8);
            } else {
                const float *p0, *p1;
                if (kb < 4) {
                    p0 = x + (size_t)v0 * 128 + kb * 32 + lg * 8;
                    p1 = x + (size_t)v1 * 128 + kb * 32 + lg * 8;
                } else {
                    p0 = u0 + (kb - 8) * 32 + lg * 8;
                    p1 = u1 + (kb - 8) * 32 + lg * 8;
                }
                a0 = load8f_bf(p0);
                a1 = load8f_bf(p1);
            }
            const short* wb = Wp + (size_t)kb * 4096;
#pragma unroll
            for (int n0 = 0; n0 < 8; ++n0) {
                bfrag b = *(const bfrag*)(wb + ((n0 * 16 + lr) * 4 + lg) * 8);
                acc[0][n0] = __builtin_amdgcn_mfma_f32_16x16x32_bf16(a0, b, acc[0][n0], 0, 0, 0);
                acc[1][n0] = __builtin_amdgcn_mfma_f32_16x16x32_bf16(a1, b, acc[1][n0], 0, 0, 0);
            }
        }
#pragma unroll
        for (int n0 = 0; n0 < 8; ++n0) {
            const int c = n0 * 16 + lr;
            float p = 0.f, q = 0.f;
#pragma unroll
            for (int t = 0; t < 2; ++t) {
                const int rbase = m0 + t * 16 + lg * 4;
#pragma unroll
                for (int r = 0; r < 4; ++r) {
                    float v = acc[t][n0][r];
                    p += v; q += v * v;
                    T2[(size_t)(rbase + r) * 128 + c] = f2bf(v);
                }
            }
            p += __shfl_xor(p, 16); p += __shfl_xor(p, 32);
            q += __shfl_xor(q, 16); q += __shfl_xor(q, 32);
            if (lg == 0) { atomicAdd(&ls[c], p); atomicAdd(&ls[128 + c], q); }
        }
    }
    __syncthreads();
    atomicAdd(&stats[threadIdx.x], ls[threadIdx.x]);
}

// Node GEMM2: out = selu(BN(T2)) @ W2b + b2b   (f32 output)
__global__ __launch_bounds__(256) void gemm4_node(
    const short* __restrict__ T2, const float* __restrict__ bnp,
    const short* __restrict__ Wp, const float* __restrict__ b2b,
    float* __restrict__ out, int N)
{
    const int lane = threadIdx.x & 63, wave = threadIdx.x >> 6;
    const int m0 = blockIdx.x * 128 + wave * 32;
    if (m0 >= N) return;   // N % 32 == 0: remaining rows all valid
    const int lr = lane & 15, lg = lane >> 4;
    const int e0 = m0 + lr, e1 = m0 + 16 + lr;

    f32x4 acc[2][8];
#pragma unroll
    for (int n0 = 0; n0 < 8; ++n0) {
        float bias = b2b[n0 * 16 + lr];
        acc[0][n0] = (f32x4){bias, bias, bias, bias};
        acc[1][n0] = (f32x4){bias, bias, bias, bias};
    }
#pragma unroll
    for (int kb = 0; kb < 4; ++kb) {
        const int koff = kb * 32 + lg * 8;
        float4 sc0 = *(const float4*)(bnp + koff);
        float4 sc1 = *(const float4*)(bnp + koff + 4);
        float4 sh0 = *(const float4*)(bnp + 128 + koff);
        float4 sh1 = *(const float4*)(bnp + 128 + koff + 4);
        float scl[8] = {sc0.x, sc0.y, sc0.z, sc0.w, sc1.x, sc1.y, sc1.z, sc1.w};
        float shf[8] = {sh0.x, sh0.y, sh0.z, sh0.w, sh1.x, sh1.y, sh1.z, sh1.w};
        bfrag r0 = *(const bfrag*)(T2 + (size_t)e0 * 128 + koff);
        bfrag r1 = *(const bfrag*)(T2 + (size_t)e1 * 128 + koff);
        bfrag a0, a1;
#pragma unroll
        for (int j = 0; j < 8; ++j) {
            a0[j] = f2bf(selu_f(bf2f(r0[j]) * scl[j] + shf[j]));
            a1[j] = f2bf(selu_f(bf2f(r1[j]) * scl[j] + shf[j]));
        }
        const short* wb = Wp + (size_t)kb * 4096;
#pragma unroll
        for (int n0 = 0; n0 < 8; ++n0) {
            bfrag b = *(const bfrag*)(wb + ((n0 * 16 + lr) * 4 + lg) * 8);
            acc[0][n0] = __builtin_amdgcn_mfma_f32_16x16x32_bf16(a0, b, acc[0][n0], 0, 0, 0);
            acc[1][n0] = __builtin_amdgcn_mfma_f32_16x16x32_bf16(a1, b, acc[1][n0], 0, 0, 0);
        }
    }
#pragma unroll
    for (int t = 0; t < 2; ++t) {
        const int rbase = m0 + t * 16 + lg * 4;
#pragma unroll
        for (int n0 = 0; n0 < 8; ++n0) {
            const int c = n0 * 16 + lr;
#pragma unroll
            for (int r = 0; r < 4; ++r)
                out[(size_t)(rbase + r) * 128 + c] = acc[t][n0][r];
        }
    }
}

// ---------------------------------------------------------------------------
// Workspace layout (bytes):
//   0        Wp1a 49152   | 49152  Wp1b 32768 | 81920 Wp2a 98304 | 180224 Wp2b 32768
//   212992   stats1 1024  | 214016 bnp1 1024  | 215040 stats2 1024 | 216064 bnp2 1024
//   217088   CNTi  400000 | 617088 OFF 400000 | 1017088 CUR 400000
//   1417088  BSUM  1024   | 1418112 BOFF 1024
//   1419136  PERM  3200000
//   4619136  T2 bf16 100000x128 (25600000)
//   30219136 Agg bf16 100000x128 (25600000)
//   55819136 T1 bf16 800000x128 (204800000)   [gemm2 writes in-place]
//   total: 260619136
// ---------------------------------------------------------------------------
extern "C" void kernel_launch(void* const* d_in, const int* in_sizes, int n_in,
                              void* d_out, int out_size, void* d_ws, size_t ws_size,
                              hipStream_t stream)
{
    const float* x   = (const float*)d_in[0];
    const float* ea  = (const float*)d_in[1];
    const float* u   = (const float*)d_in[2];
    const float* W1a = (const float*)d_in[3];
    // d_in[4] = b1a: cancels in BN
    const float* g1  = (const float*)d_in[5];
    const float* be1 = (const float*)d_in[6];
    const float* W1b = (const float*)d_in[7];
    const float* b1b = (const float*)d_in[8];
    const float* W2a = (const float*)d_in[9];
    // d_in[10] = b2a: cancels in BN
    const float* g2  = (const float*)d_in[11];
    const float* be2 = (const float*)d_in[12];
    const float* W2b = (const float*)d_in[13];
    const float* b2b = (const float*)d_in[14];
    const int* ei    = (const int*)d_in[15];
    const int* rowI  = ei;
    const int* colI  = ei + N_EDGES;
    const int* batch = (const int*)d_in[16];
    float* out = (float*)d_out;

    if (ws_size < 260619136ull) return;

    char* ws = (char*)d_ws;
    short* Wp1a   = (short*)(ws + 0);
    short* Wp1b   = (short*)(ws + 49152);
    short* Wp2a   = (short*)(ws + 81920);
    short* Wp2b   = (short*)(ws + 180224);
    float* stats1 = (float*)(ws + 212992);
    float* bnp1   = (float*)(ws + 214016);
    float* stats2 = (float*)(ws + 215040);
    float* bnp2   = (float*)(ws + 216064);
    int*   CNTi   = (int*)(ws + 217088);
    int*   OFF    = (int*)(ws + 617088);
    int*   CUR    = (int*)(ws + 1017088);
    int*   BSUM   = (int*)(ws + 1417088);
    int*   BOFF   = (int*)(ws + 1418112);
    int*   PERM   = (int*)(ws + 1419136);
    short* T2     = (short*)(ws + 4619136);
    short* Agg    = (short*)(ws + 30219136ull);
    short* T1     = (short*)(ws + 55819136ull);

    hipMemsetAsync(stats1, 0, 4096, stream);          // stats1,bnp1,stats2,bnp2
    hipMemsetAsync(CNTi, 0, 1200000, stream);         // CNTi, OFF (rewritten), CUR

    pack_w<<<96, 256, 0, stream>>>(W1a, Wp1a, 192);
    pack_w<<<64, 256, 0, stream>>>(W1b, Wp1b, 128);
    pack_w<<<192, 256, 0, stream>>>(W2a, Wp2a, 384);
    pack_w<<<64, 256, 0, stream>>>(W2b, Wp2b, 128);

    // CSR build
    hist_k<<<(N_EDGES + 255) / 256, 256, 0, stream>>>(colI, CNTi, N_EDGES);
    scan1<<<98, 1024, 0, stream>>>(CNTi, OFF, BSUM, N_NODES);
    scan2<<<1, 128, 0, stream>>>(BSUM, BOFF, 98);
    scan3<<<98, 1024, 0, stream>>>(OFF, BOFF, N_NODES);
    fill_k<<<(N_EDGES + 255) / 256, 256, 0, stream>>>(colI, OFF, CUR, PERM, N_EDGES);

    // edge MLP
    gemm1_edge<<<N_EDGES / 128, 256, 0, stream>>>(x, ea, rowI, Wp1a, T1, stats1, N_EDGES);
    bn_final<<<1, 128, 0, stream>>>(stats1, g1, be1, bnp1, 1.0f / (float)N_EDGES);
    gemm2_edge<<<N_EDGES / 128, 256, 0, stream>>>(T1, bnp1, Wp1b, b1b, N_EDGES);

    // scatter-mean
    segsum<<<2048, 256, 0, stream>>>(T1, OFF, CNTi, PERM, Agg, N_NODES);

    // node MLP
    gemm3_node<<<(N_NODES + 127) / 128, 256, 0, stream>>>(x, Agg, u, batch, Wp2a, T2, stats2, N_NODES);
    bn_final<<<1, 128, 0, stream>>>(stats2, g2, be2, bnp2, 1.0f / (float)N_NODES);
    gemm4_node<<<(N_NODES + 127) / 128, 256, 0, stream>>>(T2, bnp2, Wp2b, b2b, out, N_NODES);
}